// Round 10
// baseline (244.719 us; speedup 1.0000x reference)
//
#include <hip/hip_runtime.h>
#include <stdint.h>

// Problem constants
#define B_ 2
#define S_ 2048
#define E_ 1024
#define H_ 16
#define D_ 64
// M = B_*S_ = 4096 rows for all projection GEMMs; N=K=1024.

typedef __attribute__((ext_vector_type(8))) short bf16x8;   // 8 bf16 (4 VGPRs) MFMA A/B frag
typedef __attribute__((ext_vector_type(4))) float f32x4;    // MFMA C/D frag
typedef __attribute__((ext_vector_type(4))) short s16x4_t;  // 8B packed bf16 store

// fp32 -> bf16 RNE (bit trick; inputs finite)
__device__ __forceinline__ short bfbits(float x) {
    union { float f; uint32_t u; } v; v.f = x;
    uint32_t r = v.u + 0x7fffu + ((v.u >> 16) & 1u);
    return (short)(r >> 16);
}
// fp32 -> bf16 truncation (1 op; for P >= 0)
__device__ __forceinline__ short bfbits_trunc(float x) {
    union { float f; uint32_t u; } v; v.f = x;
    return (short)(v.u >> 16);
}

// async global->LDS, 16B per lane. LDS dest = wave-uniform base + lane*16.
__device__ __forceinline__ void async16(const short* g, short* l) {
    __builtin_amdgcn_global_load_lds((const __attribute__((address_space(1))) void*)g,
                                     (__attribute__((address_space(3))) void*)l,
                                     16, 0, 0);
}

// ---------------------------------------------------------------------------
// Kernel 1: convert + transpose WEIGHTS only (X conversion is now fused
// into gemm_qkv's A-staging). W[k][n] fp32 -> Wt[n][k] bf16. 1024 blocks.
// ---------------------------------------------------------------------------
__global__ __launch_bounds__(256) void cvt_w(const float* __restrict__ Wq,
                                             const float* __restrict__ Wk,
                                             const float* __restrict__ Wv,
                                             const float* __restrict__ Wo,
                                             short* __restrict__ dstW) {
    __shared__ short t[64][72];
    int wbid = blockIdx.x;  // 0..1023
    int z = wbid >> 8;
    const float* W = (z == 0) ? Wq : (z == 1) ? Wk : (z == 2) ? Wv : Wo;
    short* o = dstW + (size_t)z * 1048576;
    int rem = wbid & 255;
    int n0 = (rem & 15) * 64, k0 = (rem >> 4) * 64;
    int tid = threadIdx.x;
    int r = tid >> 4, c4 = tid & 15;
    for (int rep = 0; rep < 4; rep++) {
        int kk = rep * 16 + r;
        float4 x = *(const float4*)&W[(size_t)(k0 + kk) * 1024 + n0 + c4 * 4];
        t[c4 * 4 + 0][kk] = bfbits(x.x);
        t[c4 * 4 + 1][kk] = bfbits(x.y);
        t[c4 * 4 + 2][kk] = bfbits(x.z);
        t[c4 * 4 + 3][kk] = bfbits(x.w);
    }
    __syncthreads();
    int n = tid >> 3, c8 = tid & 7;
    for (int rep = 0; rep < 2; rep++) {
        int nn = rep * 32 + n;
        bf16x8 vv;
        for (int jj = 0; jj < 8; jj++) vv[jj] = t[nn][c8 * 8 + jj];
        *(bf16x8*)&o[(size_t)(n0 + nn) * 1024 + k0 + c8 * 8] = vv;
    }
}

// ---------------------------------------------------------------------------
// GEMM core v4 (K-split, bf16 A): unchanged from r9 — used by gemm_o.
// 512 threads = 2 K-groups; partials combined via LDS; group 0 epilogue.
// ---------------------------------------------------------------------------
__device__ __forceinline__ void gemm_core512(const short* __restrict__ A,
                                             const short* __restrict__ Bt,
                                             const float* __restrict__ bias,
                                             short* __restrict__ outB,
                                             float* __restrict__ outF,
                                             int mode, float scale,
                                             int m0, int n0) {
    __shared__ short As[2][2][128 * 32];  // [kg][buf][row*32+k] swizzled
    __shared__ short Bs[2][2][128 * 32];
    int tid = threadIdx.x;
    int kg = tid >> 8;
    int t256 = tid & 255;
    int lane = tid & 63, w4 = t256 >> 6;
    int col = lane & 15, quad = lane >> 4;
    int wm = (w4 >> 1) * 64, wn = (w4 & 1) * 64;
    f32x4 acc[4][4];
    for (int i = 0; i < 4; i++)
        for (int j = 0; j < 4; j++) acc[i][j] = (f32x4){0.f, 0.f, 0.f, 0.f};

    int r4 = lane >> 2;
    int skoff = ((lane & 3) ^ ((r4 >> 1) & 3)) * 8;  // shorts
    const short* ga = A + (size_t)(m0 + r4) * 1024 + kg * 512 + skoff;
    const short* gb = Bt + (size_t)(n0 + r4) * 1024 + kg * 512 + skoff;
    int fro = (quad ^ ((col >> 1) & 3)) * 8;  // swizzled 16B slot (shorts)

    auto stage = [&](int t, int b) {
        int k0_ = t * 32;
        for (int c = 0; c < 2; ++c) {
            int rb = w4 * 32 + c * 16;
            async16(ga + (size_t)rb * 1024 + k0_, &As[kg][b][rb * 32]);
            async16(gb + (size_t)rb * 1024 + k0_, &Bs[kg][b][rb * 32]);
        }
    };

    stage(0, 0);
    __syncthreads();
    for (int t = 0; t < 16; ++t) {
        int cur = t & 1;
        if (t + 1 < 16) stage(t + 1, cur ^ 1);
        bf16x8 af[4], bfr[4];
        for (int i = 0; i < 4; i++)
            af[i] = *(const bf16x8*)&As[kg][cur][(wm + i * 16 + col) * 32 + fro];
        for (int j = 0; j < 4; j++)
            bfr[j] = *(const bf16x8*)&Bs[kg][cur][(wn + j * 16 + col) * 32 + fro];
        for (int i = 0; i < 4; i++)
            for (int j = 0; j < 4; j++)
                acc[i][j] = __builtin_amdgcn_mfma_f32_16x16x32_bf16(af[i], bfr[j], acc[i][j], 0, 0, 0);
        __syncthreads();
    }

    float* cb = (float*)&As[0][0][0];
    for (int i = 0; i < 4; i++) {
        if (kg == 1) {
            f32x4* dst = (f32x4*)(cb + t256 * 17);
            for (int j = 0; j < 4; j++) dst[j] = acc[i][j];
        }
        __syncthreads();
        if (kg == 0) {
            const f32x4* src = (const f32x4*)(cb + t256 * 17);
            for (int j = 0; j < 4; j++) {
                f32x4 s = src[j];
                for (int r = 0; r < 4; r++) acc[i][j][r] += s[r];
            }
        }
        __syncthreads();
    }

    if (kg != 0) return;
    int mbase = m0 + wm + quad * 4;
    for (int i = 0; i < 4; i++) {
        int mb = mbase + i * 16;
        for (int j = 0; j < 4; j++) {
            int n = n0 + wn + j * 16 + col;
            float bv_ = bias[n];
            if (mode == 0) {
                for (int r = 0; r < 4; r++)
                    outB[(size_t)(mb + r) * 1024 + n] = bfbits((acc[i][j][r] + bv_) * scale);
            } else if (mode == 1) {
                int b_ = mb >> 11, s_ = mb & 2047;
                size_t base = (((size_t)(b_ * 16 + (n >> 6)) * 64) + (n & 63)) * 2048 + s_;
                s16x4_t pv;
                for (int r = 0; r < 4; r++) pv[r] = bfbits((acc[i][j][r] + bv_) * scale);
                *(s16x4_t*)&outB[base] = pv;
            } else {
                for (int r = 0; r < 4; r++)
                    outF[(size_t)(mb + r) * 1024 + n] = (acc[i][j][r] + bv_) * scale;
            }
        }
    }
}

// ---------------------------------------------------------------------------
// Fused QKV projections with ON-THE-FLY fp32->bf16 A conversion (removes
// the 48MB-read/24MB-write X conversion pass entirely). Same K-split
// structure/swizzle as gemm_core512; A is reg-staged (T14 issue-early /
// write-late: float4 loads issued before compute(t), cvt+ds_write after),
// producing a bit-identical LDS image to the gload_lds path (slot parity
// (row>>1)&3 is invariant under the +16-row offset). B stays gload_lds.
// grid 768 x 512, bijective XCD swizzle (768 = 8 * 96).
// ---------------------------------------------------------------------------
#define QSCALE (0.015625f * 1.44269504088896340736f)
__global__ __launch_bounds__(512, 4) void gemm_qkv(const float* __restrict__ q,
                                                   const float* __restrict__ k,
                                                   const float* __restrict__ v,
                                                   const short* __restrict__ Wb,
                                                   const float* __restrict__ bq,
                                                   const float* __restrict__ bk,
                                                   const float* __restrict__ bv,
                                                   short* __restrict__ Qp) {
    __shared__ short As[2][2][128 * 32];  // [kg][buf][row*32+k] swizzled
    __shared__ short Bs[2][2][128 * 32];
    int bid = blockIdx.x;
    int L = (bid & 7) * 96 + (bid >> 3);  // bijective: 768 = 8 * 96
    int z = L >> 8;                        // 0..2
    int rem = L & 255;
    int m0 = (rem >> 3) * 128, n0 = (rem & 7) * 128;
    const float* A32 = (z == 0) ? q : (z == 1) ? k : v;
    const short* Bt = Wb + (size_t)z * 1048576;
    const float* bias = (z == 0) ? bq : (z == 1) ? bk : bv;
    short* outB = Qp + (size_t)z * 4194304;  // Qp, Kp, VpT contiguous
    int mode = (z == 2) ? 1 : 0;
    float scale = (z == 0) ? QSCALE : 1.0f;

    int tid = threadIdx.x;
    int kg = tid >> 8;
    int t256 = tid & 255;
    int lane = tid & 63, w4 = t256 >> 6;
    int col = lane & 15, quad = lane >> 4;
    int wm = (w4 >> 1) * 64, wn = (w4 & 1) * 64;
    f32x4 acc[4][4];
    for (int i = 0; i < 4; i++)
        for (int j = 0; j < 4; j++) acc[i][j] = (f32x4){0.f, 0.f, 0.f, 0.f};

    int r4 = lane >> 2, lslot = lane & 3;
    int gsl = (lslot ^ ((r4 >> 1) & 3)) * 8;  // swizzled source slot (elems)
    // A fp32 source rows (c=0,1); slot parity identical for both
    int rowc0 = w4 * 32 + r4, rowc1 = rowc0 + 16;
    const float* gA0 = A32 + (size_t)(m0 + rowc0) * 1024 + kg * 512 + gsl;
    const float* gA1 = A32 + (size_t)(m0 + rowc1) * 1024 + kg * 512 + gsl;
    int ldsA0 = rowc0 * 32 + lslot * 8;  // shorts
    int ldsA1 = rowc1 * 32 + lslot * 8;
    const short* gb = Bt + (size_t)(n0 + r4) * 1024 + kg * 512 + gsl;
    int fro = (quad ^ ((col >> 1) & 3)) * 8;

    float4 pa0, pa1, pa2, pa3;  // staged A (named regs; rule #20)
    auto loadA = [&](int t) {
        int k0_ = t * 32;
        pa0 = *(const float4*)(gA0 + k0_);
        pa1 = *(const float4*)(gA0 + k0_ + 4);
        pa2 = *(const float4*)(gA1 + k0_);
        pa3 = *(const float4*)(gA1 + k0_ + 4);
    };
    auto writeA = [&](int b) {
        s16x4_t w0, w1, w2, w3;
        w0[0] = bfbits(pa0.x); w0[1] = bfbits(pa0.y); w0[2] = bfbits(pa0.z); w0[3] = bfbits(pa0.w);
        w1[0] = bfbits(pa1.x); w1[1] = bfbits(pa1.y); w1[2] = bfbits(pa1.z); w1[3] = bfbits(pa1.w);
        w2[0] = bfbits(pa2.x); w2[1] = bfbits(pa2.y); w2[2] = bfbits(pa2.z); w2[3] = bfbits(pa2.w);
        w3[0] = bfbits(pa3.x); w3[1] = bfbits(pa3.y); w3[2] = bfbits(pa3.z); w3[3] = bfbits(pa3.w);
        *(s16x4_t*)&As[kg][b][ldsA0] = w0;
        *(s16x4_t*)&As[kg][b][ldsA0 + 4] = w1;
        *(s16x4_t*)&As[kg][b][ldsA1] = w2;
        *(s16x4_t*)&As[kg][b][ldsA1 + 4] = w3;
    };
    auto stageB = [&](int t, int b) {
        int k0_ = t * 32;
        for (int c = 0; c < 2; ++c) {
            int rb = w4 * 32 + c * 16;
            async16(gb + (size_t)rb * 1024 + k0_, &Bs[kg][b][rb * 32]);
        }
    };

    loadA(0);
    stageB(0, 0);
    writeA(0);        // waits the fp32 loads, converts, ds_writes
    __syncthreads();  // drains B gload_lds + A ds_writes
    for (int t = 0; t < 16; ++t) {
        int cur = t & 1;
        if (t + 1 < 16) { loadA(t + 1); stageB(t + 1, cur ^ 1); }
        bf16x8 af[4], bfr[4];
        for (int i = 0; i < 4; i++)
            af[i] = *(const bf16x8*)&As[kg][cur][(wm + i * 16 + col) * 32 + fro];
        for (int j = 0; j < 4; j++)
            bfr[j] = *(const bf16x8*)&Bs[kg][cur][(wn + j * 16 + col) * 32 + fro];
        for (int i = 0; i < 4; i++)
            for (int j = 0; j < 4; j++)
                acc[i][j] = __builtin_amdgcn_mfma_f32_16x16x32_bf16(af[i], bfr[j], acc[i][j], 0, 0, 0);
        if (t + 1 < 16) writeA(cur ^ 1);  // cvt lands after compute(t)
        __syncthreads();
    }

    // combine kg1 -> kg0 via LDS (stride 17 floats = conflict-free)
    float* cb = (float*)&As[0][0][0];
    for (int i = 0; i < 4; i++) {
        if (kg == 1) {
            f32x4* dst = (f32x4*)(cb + t256 * 17);
            for (int j = 0; j < 4; j++) dst[j] = acc[i][j];
        }
        __syncthreads();
        if (kg == 0) {
            const f32x4* src = (const f32x4*)(cb + t256 * 17);
            for (int j = 0; j < 4; j++) {
                f32x4 s = src[j];
                for (int r = 0; r < 4; r++) acc[i][j][r] += s[r];
            }
        }
        __syncthreads();
    }

    if (kg != 0) return;
    int mbase = m0 + wm + quad * 4;
    for (int i = 0; i < 4; i++) {
        int mb = mbase + i * 16;
        for (int j = 0; j < 4; j++) {
            int n = n0 + wn + j * 16 + col;
            float bv_ = bias[n];
            if (mode == 0) {
                for (int r = 0; r < 4; r++)
                    outB[(size_t)(mb + r) * 1024 + n] = bfbits((acc[i][j][r] + bv_) * scale);
            } else {
                int b_ = mb >> 11, s_ = mb & 2047;
                size_t base = (((size_t)(b_ * 16 + (n >> 6)) * 64) + (n & 63)) * 2048 + s_;
                s16x4_t pv;
                for (int r = 0; r < 4; r++) pv[r] = bfbits((acc[i][j][r] + bv_) * scale);
                *(s16x4_t*)&outB[base] = pv;
            }
        }
    }
}

// Output projection: 1D grid 256 blocks x 512 threads, XCD chunking.
__global__ __launch_bounds__(512, 4) void gemm_o(const short* __restrict__ Ctx,
                                                 const short* __restrict__ Wob,
                                                 const float* __restrict__ bo,
                                                 float* __restrict__ out) {
    int bid = blockIdx.x;
    int L = (bid & 7) * 32 + (bid >> 3);  // bijective: 256 = 8 * 32
    int m0 = (L >> 3) * 128, n0 = (L & 7) * 128;
    gemm_core512(Ctx, Wob, bo, nullptr, out, 2, 1.0f, m0, n0);
}

// ---------------------------------------------------------------------------
// Flash-style causal attention, v10 (unchanged from r8 — proven 46.5 µs):
// 8-wave TLP, block 512: waves 0-3 q-tile qx, waves 4-7 q-tile 31-qx,
// sharing one staged K/V pipeline; bijective XCD chunking bh-major;
// row-sum via MFMA ones-column. LDS 50.4 KB -> 2 blocks/CU.
// ---------------------------------------------------------------------------
__device__ __forceinline__ void stage_kv8(const short* __restrict__ Kp,
                                          const short* __restrict__ VpT,
                                          short* Kbuf, short* Vbuf,
                                          int b, int bh, int h, int kv0,
                                          int tid) {
    int row = tid >> 3;                    // 0..63 (512 threads cover tile)
    int sk = ((tid & 7) ^ (row & 7)) * 8;  // inverse-swizzled 16B slot (shorts)
    int wbase = (tid >> 6) * 512;          // wave-uniform LDS base (shorts)
    async16(Kp + (size_t)(b * 2048 + kv0 + row) * 1024 + h * 64 + sk, &Kbuf[wbase]);
    async16(VpT + (size_t)(bh * 64 + row) * 2048 + kv0 + sk, &Vbuf[wbase]);
}

__global__ __launch_bounds__(512) void attn_kernel(const short* __restrict__ Qp,
                                                   const short* __restrict__ Kp,
                                                   const short* __restrict__ VpT,
                                                   short* __restrict__ Ctx) {
    __shared__ short Kt[2][64 * 64];  // [buf][kv][d] swizzled, 8 KB each
    __shared__ short Vt[2][64 * 64];  // [buf][d][kv] swizzled
    __shared__ short Pl[8][16 * 72];  // per-wave P, [q_local][kv(72 stride)]
    int tid = threadIdx.x, lane = tid & 63, w = tid >> 6;
    int col = lane & 15, quad = lane >> 4;
    int c7 = col & 7;
    int bid = blockIdx.x;
    int L = (bid & 7) * 64 + (bid >> 3);  // bijective XCD chunking (512 = 8*64)
    int qx = L & 15, bh = L >> 4;          // 4 bh per XCD -> K/V L2-resident
    int b = bh >> 4, h = bh & 15;
    int wi = w & 3;
    int qt = (w < 4) ? qx : (31 - qx);     // wave's q-tile
    int myN = qt + 1;                      // wave's causal kv-tile count
    int nB = 32 - qx;                      // block loop bound (= max)
    int qrow = qt * 64 + wi * 16;          // wave's q base

    bf16x8 ones;
    for (int j = 0; j < 8; j++) ones[j] = (short)0x3F80;  // bf16 1.0

    bf16x8 aq0, aq1;
    {
        const short* qa = Qp + ((size_t)(b * 2048 + qrow + col)) * 1024 + h * 64;
        aq0 = *(const bf16x8*)(qa + quad * 8);
        aq1 = *(const bf16x8*)(qa + 32 + quad * 8);
    }
    f32x4 o[4];
    for (int dj = 0; dj < 4; dj++) o[dj] = (f32x4){0.f, 0.f, 0.f, 0.f};
    f32x4 psv = (f32x4){0.f, 0.f, 0.f, 0.f};  // row-sums via MFMA ones

    short* Plw = Pl[w];

    stage_kv8(Kp, VpT, Kt[0], Vt[0], b, bh, h, 0, tid);

    for (int t = 0; t < nB; t++) {
        __syncthreads();  // stage(t) landed; prev compute done
        if (t + 1 < nB)
            stage_kv8(Kp, VpT, Kt[(t + 1) & 1], Vt[(t + 1) & 1], b, bh, h,
                      (t + 1) * 64, tid);
        if (t < myN) {  // wave-uniform predicate (A-waves idle past nA)
            const short* Kb = Kt[t & 1];
            const short* Vb = Vt[t & 1];

            f32x4 sf[4];
            for (int i = 0; i < 4; i++) sf[i] = (f32x4){0.f, 0.f, 0.f, 0.f};
            __builtin_amdgcn_s_setprio(1);
            for (int ks = 0; ks < 2; ks++) {
                bf16x8 bq_ = ks ? aq1 : aq0;
                int sl = ((ks * 4 + quad) ^ c7) * 8;
                for (int i = 0; i < 4; i++) {
                    bf16x8 ak_ = *(const bf16x8*)&Kb[(i * 16 + col) * 64 + sl];
                    sf[i] = __builtin_amdgcn_mfma_f32_16x16x32_bf16(ak_, bq_, sf[i], 0, 0, 0);
                }
            }
            __builtin_amdgcn_s_setprio(0);
            if (t == myN - 1) {
                int qg = qrow + col;
                for (int i = 0; i < 4; i++) {
                    int kvg = t * 64 + i * 16 + quad * 4;
                    for (int r = 0; r < 4; r++)
                        if (kvg + r > qg) sf[i][r] = -3.0e38f;
                }
            }
            for (int i = 0; i < 4; i++) {
                s16x4_t pw;
                for (int r = 0; r < 4; r++)
                    pw[r] = bfbits_trunc(exp2f(sf[i][r]));
                *(s16x4_t*)&Plw[col * 72 + i * 16 + quad * 4] = pw;
            }
            __builtin_amdgcn_s_setprio(1);
            for (int ks = 0; ks < 2; ks++) {
                bf16x8 ap = *(const bf16x8*)&Plw[col * 72 + ks * 32 + quad * 8];
                int sl = ((ks * 4 + quad) ^ c7) * 8;
                psv = __builtin_amdgcn_mfma_f32_16x16x32_bf16(ap, ones, psv, 0, 0, 0);
                for (int dj = 0; dj < 4; dj++) {
                    bf16x8 bv_ = *(const bf16x8*)&Vb[(dj * 16 + col) * 64 + sl];
                    o[dj] = __builtin_amdgcn_mfma_f32_16x16x32_bf16(ap, bv_, o[dj], 0, 0, 0);
                }
            }
            __builtin_amdgcn_s_setprio(0);
        }
    }
    float inv[4];
    for (int r = 0; r < 4; r++) inv[r] = 1.0f / psv[r];
    for (int r = 0; r < 4; r++) {
        for (int dj = 0; dj < 4; dj++) {
            float val = o[dj][r] * inv[r];
            Ctx[((size_t)(b * 2048 + qrow + quad * 4 + r)) * 1024 + h * 64 + dj * 16 + col] = bfbits(val);
        }
    }
}

// ---------------------------------------------------------------------------
extern "C" void kernel_launch(void* const* d_in, const int* in_sizes, int n_in,
                              void* d_out, int out_size, void* d_ws, size_t ws_size,
                              hipStream_t stream) {
    const float* q  = (const float*)d_in[0];
    const float* k  = (const float*)d_in[1];
    const float* v  = (const float*)d_in[2];
    const float* Wq = (const float*)d_in[3];
    const float* Wk = (const float*)d_in[4];
    const float* Wv = (const float*)d_in[5];
    const float* Wo = (const float*)d_in[6];
    const float* bq = (const float*)d_in[7];
    const float* bk = (const float*)d_in[8];
    const float* bv = (const float*)d_in[9];
    const float* bo = (const float*)d_in[10];
    // d_in[11] = causal mask (known structure; not read)

    // workspace layout (element offsets, bf16 stored as short).
    short* wsb = (short*)d_ws;
    short* Wb  = wsb;                       // 4 x 1048576  (Wq^T,Wk^T,Wv^T,Wo^T)
    short* Qp  = Wb + 4 * 1048576;          // 4194304  (B,S,H,D), scales folded
    short* Kp  = Qp + 4194304;              // 4194304  (B,S,H,D)
    short* VpT = Kp + 4194304;              // 4194304  (B,H,D,S)
    short* Ctx = VpT + 4194304;             // 4194304  (B,S,H,D)

    cvt_w<<<1024, 256, 0, stream>>>(Wq, Wk, Wv, Wo, Wb);
    gemm_qkv<<<768, 512, 0, stream>>>(q, k, v, Wb, bq, bk, bv, Qp);
    attn_kernel<<<512, 512, 0, stream>>>(Qp, Kp, VpT, Ctx);
    gemm_o<<<256, 512, 0, stream>>>(Ctx, Wb + 3 * 1048576, bo, (float*)d_out);
}

// Round 11
// 237.003 us; speedup vs baseline: 1.0326x; 1.0326x over previous
//
#include <hip/hip_runtime.h>
#include <stdint.h>

// Problem constants
#define B_ 2
#define S_ 2048
#define E_ 1024
#define H_ 16
#define D_ 64
// M = B_*S_ = 4096 rows for all projection GEMMs; N=K=1024.

typedef __attribute__((ext_vector_type(8))) short bf16x8;   // 8 bf16 (4 VGPRs) MFMA A/B frag
typedef __attribute__((ext_vector_type(4))) float f32x4;    // MFMA C/D frag
typedef __attribute__((ext_vector_type(4))) short s16x4_t;  // 8B packed bf16 store

// Counted-vmcnt barrier discipline (T4): keep the newest prefetch loads in
// flight across the barrier instead of __syncthreads()'s vmcnt(0) drain.
#define WAITV4 asm volatile("s_waitcnt vmcnt(4)" ::: "memory")
#define WAITV2 asm volatile("s_waitcnt vmcnt(2)" ::: "memory")
#define WAITV0 asm volatile("s_waitcnt vmcnt(0)" ::: "memory")
#define BARRIER do { asm volatile("" ::: "memory"); __builtin_amdgcn_s_barrier(); asm volatile("" ::: "memory"); } while (0)

// fp32 -> bf16 RNE (bit trick; inputs finite)
__device__ __forceinline__ short bfbits(float x) {
    union { float f; uint32_t u; } v; v.f = x;
    uint32_t r = v.u + 0x7fffu + ((v.u >> 16) & 1u);
    return (short)(r >> 16);
}
// fp32 -> bf16 truncation (1 op; for P >= 0)
__device__ __forceinline__ short bfbits_trunc(float x) {
    union { float f; uint32_t u; } v; v.f = x;
    return (short)(v.u >> 16);
}

// async global->LDS, 16B per lane. LDS dest = wave-uniform base + lane*16.
__device__ __forceinline__ void async16(const short* g, short* l) {
    __builtin_amdgcn_global_load_lds((const __attribute__((address_space(1))) void*)g,
                                     (__attribute__((address_space(3))) void*)l,
                                     16, 0, 0);
}

// ---------------------------------------------------------------------------
// Kernel 1 (merged): blocks [0,12288) convert q,k,v fp32 -> bf16;
// blocks [12288, 13312) convert + transpose the 4 weights.
// (r10's in-GEMM A conversion reverted: it put fp32-load-wait + cvt on the
// barrier-locked critical path, +23 µs on gemm_qkv.)
// ---------------------------------------------------------------------------
__global__ __launch_bounds__(256) void cvt_all(const float* __restrict__ q,
                                               const float* __restrict__ k,
                                               const float* __restrict__ v,
                                               const float* __restrict__ Wq,
                                               const float* __restrict__ Wk,
                                               const float* __restrict__ Wv,
                                               const float* __restrict__ Wo,
                                               short* __restrict__ dstX,
                                               short* __restrict__ dstW) {
    __shared__ short t[64][72];  // weights path only
    int bid = blockIdx.x;
    if (bid < 12288) {
        const long long NV = 1048576;  // vec4 count per tensor
        long long i = (long long)bid * 256 + threadIdx.x;  // 0 .. 3*NV-1
        const float* src = (i < NV) ? q : (i < 2 * NV) ? k : v;
        long long j = (i >= 2 * NV) ? (i - 2 * NV) : (i >= NV) ? (i - NV) : i;
        float4 x = ((const float4*)src)[j];
        s16x4_t o;
        o[0] = bfbits(x.x); o[1] = bfbits(x.y); o[2] = bfbits(x.z); o[3] = bfbits(x.w);
        ((s16x4_t*)dstX)[i] = o;
        return;
    }
    int wbid = bid - 12288;  // 0..1023
    int z = wbid >> 8;
    const float* W = (z == 0) ? Wq : (z == 1) ? Wk : (z == 2) ? Wv : Wo;
    short* o = dstW + (size_t)z * 1048576;
    int rem = wbid & 255;
    int n0 = (rem & 15) * 64, k0 = (rem >> 4) * 64;
    int tid = threadIdx.x;
    int r = tid >> 4, c4 = tid & 15;
    for (int rep = 0; rep < 4; rep++) {
        int kk = rep * 16 + r;
        float4 x = *(const float4*)&W[(size_t)(k0 + kk) * 1024 + n0 + c4 * 4];
        t[c4 * 4 + 0][kk] = bfbits(x.x);
        t[c4 * 4 + 1][kk] = bfbits(x.y);
        t[c4 * 4 + 2][kk] = bfbits(x.z);
        t[c4 * 4 + 3][kk] = bfbits(x.w);
    }
    __syncthreads();
    int n = tid >> 3, c8 = tid & 7;
    for (int rep = 0; rep < 2; rep++) {
        int nn = rep * 32 + n;
        bf16x8 vv;
        for (int jj = 0; jj < 8; jj++) vv[jj] = t[nn][c8 * 8 + jj];
        *(bf16x8*)&o[(size_t)(n0 + nn) * 1024 + k0 + c8 * 8] = vv;
    }
}

// ---------------------------------------------------------------------------
// GEMM core v5 (K-split + counted vmcnt): 512 threads = 2 K-groups of 256;
// group kg accumulates K in [kg*512, kg*512+512), BK=32 double-buffered.
// Per-iter: stage(t+1) -> s_waitcnt vmcnt(4) (stage(t) done, stage(t+1)
// stays in flight) -> s_barrier -> ds_read+MFMA -> s_barrier. No vmem
// drain in the loop (T4; m218 +38-73%). Partials combined via LDS;
// group 0 epilogue. 16B-slot XOR swizzle as before.
// ---------------------------------------------------------------------------
__device__ __forceinline__ void gemm_core512(const short* __restrict__ A,
                                             const short* __restrict__ Bt,
                                             const float* __restrict__ bias,
                                             short* __restrict__ outB,
                                             float* __restrict__ outF,
                                             int mode, float scale,
                                             int m0, int n0) {
    __shared__ short As[2][2][128 * 32];  // [kg][buf][row*32+k] swizzled
    __shared__ short Bs[2][2][128 * 32];
    int tid = threadIdx.x;
    int kg = tid >> 8;
    int t256 = tid & 255;
    int lane = tid & 63, w4 = t256 >> 6;
    int col = lane & 15, quad = lane >> 4;
    int wm = (w4 >> 1) * 64, wn = (w4 & 1) * 64;
    f32x4 acc[4][4];
    for (int i = 0; i < 4; i++)
        for (int j = 0; j < 4; j++) acc[i][j] = (f32x4){0.f, 0.f, 0.f, 0.f};

    int r4 = lane >> 2;
    int skoff = ((lane & 3) ^ ((r4 >> 1) & 3)) * 8;  // shorts
    const short* ga = A + (size_t)(m0 + r4) * 1024 + kg * 512 + skoff;
    const short* gb = Bt + (size_t)(n0 + r4) * 1024 + kg * 512 + skoff;
    int fro = (quad ^ ((col >> 1) & 3)) * 8;  // swizzled 16B slot (shorts)

    auto stage = [&](int t, int b) {  // 4 gload_lds per wave
        int k0_ = t * 32;
        for (int c = 0; c < 2; ++c) {
            int rb = w4 * 32 + c * 16;
            async16(ga + (size_t)rb * 1024 + k0_, &As[kg][b][rb * 32]);
            async16(gb + (size_t)rb * 1024 + k0_, &Bs[kg][b][rb * 32]);
        }
    };

    stage(0, 0);
    __syncthreads();  // prologue: full drain once, buf0 ready
    for (int t = 0; t < 16; ++t) {
        int cur = t & 1;
        if (t + 1 < 16) { stage(t + 1, cur ^ 1); WAITV4; }  // stage(t) done; t+1 in flight
        else { WAITV0; }
        BARRIER;  // all waves: buf cur fully staged
        bf16x8 af[4], bfr[4];
        for (int i = 0; i < 4; i++)
            af[i] = *(const bf16x8*)&As[kg][cur][(wm + i * 16 + col) * 32 + fro];
        for (int j = 0; j < 4; j++)
            bfr[j] = *(const bf16x8*)&Bs[kg][cur][(wn + j * 16 + col) * 32 + fro];
        for (int i = 0; i < 4; i++)
            for (int j = 0; j < 4; j++)
                acc[i][j] = __builtin_amdgcn_mfma_f32_16x16x32_bf16(af[i], bfr[j], acc[i][j], 0, 0, 0);
        BARRIER;  // readers of cur done before it is re-staged at t+2
    }

    // combine kg1 -> kg0 via LDS (stride 17 floats = conflict-free).
    // All vmem drained by final iter's WAITV0.
    float* cb = (float*)&As[0][0][0];
    for (int i = 0; i < 4; i++) {
        if (kg == 1) {
            f32x4* dst = (f32x4*)(cb + t256 * 17);
            for (int j = 0; j < 4; j++) dst[j] = acc[i][j];
        }
        __syncthreads();
        if (kg == 0) {
            const f32x4* src = (const f32x4*)(cb + t256 * 17);
            for (int j = 0; j < 4; j++) {
                f32x4 s = src[j];
                for (int r = 0; r < 4; r++) acc[i][j][r] += s[r];
            }
        }
        __syncthreads();
    }

    if (kg != 0) return;
    int mbase = m0 + wm + quad * 4;
    for (int i = 0; i < 4; i++) {
        int mb = mbase + i * 16;
        for (int j = 0; j < 4; j++) {
            int n = n0 + wn + j * 16 + col;
            float bv_ = bias[n];
            if (mode == 0) {
                for (int r = 0; r < 4; r++)
                    outB[(size_t)(mb + r) * 1024 + n] = bfbits((acc[i][j][r] + bv_) * scale);
            } else if (mode == 1) {
                int b_ = mb >> 11, s_ = mb & 2047;
                size_t base = (((size_t)(b_ * 16 + (n >> 6)) * 64) + (n & 63)) * 2048 + s_;
                s16x4_t pv;
                for (int r = 0; r < 4; r++) pv[r] = bfbits((acc[i][j][r] + bv_) * scale);
                *(s16x4_t*)&outB[base] = pv;
            } else {
                for (int r = 0; r < 4; r++)
                    outF[(size_t)(mb + r) * 1024 + n] = (acc[i][j][r] + bv_) * scale;
            }
        }
    }
}

// Fused QKV projections: 1D grid 768 blocks x 512 threads, bijective
// XCD-aware swizzle (768 = 8 * 96).
#define QSCALE (0.015625f * 1.44269504088896340736f)
__global__ __launch_bounds__(512, 4) void gemm_qkv(const short* __restrict__ Xb,
                                                   const short* __restrict__ Wb,
                                                   const float* __restrict__ bq,
                                                   const float* __restrict__ bk,
                                                   const float* __restrict__ bv,
                                                   short* __restrict__ Qp) {
    int bid = blockIdx.x;
    int L = (bid & 7) * 96 + (bid >> 3);  // bijective: 768 = 8 * 96
    int z = L >> 8;                        // 0..2
    int rem = L & 255;
    int m0 = (rem >> 3) * 128, n0 = (rem & 7) * 128;
    const short* A = Xb + (size_t)z * 4194304;
    const short* Bt = Wb + (size_t)z * 1048576;
    const float* bias = (z == 0) ? bq : (z == 1) ? bk : bv;
    short* outB = Qp + (size_t)z * 4194304;  // Qp, Kp, VpT contiguous
    gemm_core512(A, Bt, bias, outB, nullptr, (z == 2) ? 1 : 0,
                 (z == 0) ? QSCALE : 1.0f, m0, n0);
}

// Output projection: 1D grid 256 blocks x 512 threads, XCD chunking.
__global__ __launch_bounds__(512, 4) void gemm_o(const short* __restrict__ Ctx,
                                                 const short* __restrict__ Wob,
                                                 const float* __restrict__ bo,
                                                 float* __restrict__ out) {
    int bid = blockIdx.x;
    int L = (bid & 7) * 32 + (bid >> 3);  // bijective: 256 = 8 * 32
    int m0 = (L >> 3) * 128, n0 = (L & 7) * 128;
    gemm_core512(Ctx, Wob, bo, nullptr, out, 2, 1.0f, m0, n0);
}

// ---------------------------------------------------------------------------
// Flash-style causal attention, v11 = v10 (8-wave TLP, proven 46.5 µs) with
// the same counted-vmcnt barrier discipline: stage(t+1) stays in flight
// across the barrier (vmcnt(2) = this wave's 2 newest loads), 2 raw
// barriers/iter, no drain in the loop.
// Block 512: waves 0-3 q-tile qx, waves 4-7 q-tile 31-qx, shared K/V
// pipeline; bijective XCD chunking bh-major; MFMA ones-column row-sum.
// LDS 50.4 KB -> 2 blocks/CU.
// ---------------------------------------------------------------------------
__device__ __forceinline__ void stage_kv8(const short* __restrict__ Kp,
                                          const short* __restrict__ VpT,
                                          short* Kbuf, short* Vbuf,
                                          int b, int bh, int h, int kv0,
                                          int tid) {
    int row = tid >> 3;                    // 0..63 (512 threads cover tile)
    int sk = ((tid & 7) ^ (row & 7)) * 8;  // inverse-swizzled 16B slot (shorts)
    int wbase = (tid >> 6) * 512;          // wave-uniform LDS base (shorts)
    async16(Kp + (size_t)(b * 2048 + kv0 + row) * 1024 + h * 64 + sk, &Kbuf[wbase]);
    async16(VpT + (size_t)(bh * 64 + row) * 2048 + kv0 + sk, &Vbuf[wbase]);
}

__global__ __launch_bounds__(512) void attn_kernel(const short* __restrict__ Qp,
                                                   const short* __restrict__ Kp,
                                                   const short* __restrict__ VpT,
                                                   short* __restrict__ Ctx) {
    __shared__ short Kt[2][64 * 64];  // [buf][kv][d] swizzled, 8 KB each
    __shared__ short Vt[2][64 * 64];  // [buf][d][kv] swizzled
    __shared__ short Pl[8][16 * 72];  // per-wave P, [q_local][kv(72 stride)]
    int tid = threadIdx.x, lane = tid & 63, w = tid >> 6;
    int col = lane & 15, quad = lane >> 4;
    int c7 = col & 7;
    int bid = blockIdx.x;
    int L = (bid & 7) * 64 + (bid >> 3);  // bijective XCD chunking (512 = 8*64)
    int qx = L & 15, bh = L >> 4;          // 4 bh per XCD -> K/V L2-resident
    int b = bh >> 4, h = bh & 15;
    int wi = w & 3;
    int qt = (w < 4) ? qx : (31 - qx);     // wave's q-tile
    int myN = qt + 1;                      // wave's causal kv-tile count
    int nB = 32 - qx;                      // block loop bound (= max)
    int qrow = qt * 64 + wi * 16;          // wave's q base

    bf16x8 ones;
    for (int j = 0; j < 8; j++) ones[j] = (short)0x3F80;  // bf16 1.0

    bf16x8 aq0, aq1;
    {
        const short* qa = Qp + ((size_t)(b * 2048 + qrow + col)) * 1024 + h * 64;
        aq0 = *(const bf16x8*)(qa + quad * 8);
        aq1 = *(const bf16x8*)(qa + 32 + quad * 8);
    }
    f32x4 o[4];
    for (int dj = 0; dj < 4; dj++) o[dj] = (f32x4){0.f, 0.f, 0.f, 0.f};
    f32x4 psv = (f32x4){0.f, 0.f, 0.f, 0.f};  // row-sums via MFMA ones

    short* Plw = Pl[w];

    stage_kv8(Kp, VpT, Kt[0], Vt[0], b, bh, h, 0, tid);

    for (int t = 0; t < nB; t++) {
        if (t + 1 < nB) {
            stage_kv8(Kp, VpT, Kt[(t + 1) & 1], Vt[(t + 1) & 1], b, bh, h,
                      (t + 1) * 64, tid);
            WAITV2;  // stage(t) done; stage(t+1) stays in flight
        } else {
            WAITV0;
        }
        BARRIER;  // all waves: buf t&1 fully staged
        if (t < myN) {  // wave-uniform predicate (A-waves idle past nA)
            const short* Kb = Kt[t & 1];
            const short* Vb = Vt[t & 1];

            f32x4 sf[4];
            for (int i = 0; i < 4; i++) sf[i] = (f32x4){0.f, 0.f, 0.f, 0.f};
            __builtin_amdgcn_s_setprio(1);
            for (int ks = 0; ks < 2; ks++) {
                bf16x8 bq_ = ks ? aq1 : aq0;
                int sl = ((ks * 4 + quad) ^ c7) * 8;
                for (int i = 0; i < 4; i++) {
                    bf16x8 ak_ = *(const bf16x8*)&Kb[(i * 16 + col) * 64 + sl];
                    sf[i] = __builtin_amdgcn_mfma_f32_16x16x32_bf16(ak_, bq_, sf[i], 0, 0, 0);
                }
            }
            __builtin_amdgcn_s_setprio(0);
            if (t == myN - 1) {
                int qg = qrow + col;
                for (int i = 0; i < 4; i++) {
                    int kvg = t * 64 + i * 16 + quad * 4;
                    for (int r = 0; r < 4; r++)
                        if (kvg + r > qg) sf[i][r] = -3.0e38f;
                }
            }
            for (int i = 0; i < 4; i++) {
                s16x4_t pw;
                for (int r = 0; r < 4; r++)
                    pw[r] = bfbits_trunc(exp2f(sf[i][r]));
                *(s16x4_t*)&Plw[col * 72 + i * 16 + quad * 4] = pw;
            }
            __builtin_amdgcn_s_setprio(1);
            for (int ks = 0; ks < 2; ks++) {
                bf16x8 ap = *(const bf16x8*)&Plw[col * 72 + ks * 32 + quad * 8];
                int sl = ((ks * 4 + quad) ^ c7) * 8;
                psv = __builtin_amdgcn_mfma_f32_16x16x32_bf16(ap, ones, psv, 0, 0, 0);
                for (int dj = 0; dj < 4; dj++) {
                    bf16x8 bv_ = *(const bf16x8*)&Vb[(dj * 16 + col) * 64 + sl];
                    o[dj] = __builtin_amdgcn_mfma_f32_16x16x32_bf16(ap, bv_, o[dj], 0, 0, 0);
                }
            }
            __builtin_amdgcn_s_setprio(0);
        }
        BARRIER;  // readers of buf t&1 done before it is re-staged at t+2
    }
    float inv[4];
    for (int r = 0; r < 4; r++) inv[r] = 1.0f / psv[r];
    for (int r = 0; r < 4; r++) {
        for (int dj = 0; dj < 4; dj++) {
            float val = o[dj][r] * inv[r];
            Ctx[((size_t)(b * 2048 + qrow + quad * 4 + r)) * 1024 + h * 64 + dj * 16 + col] = bfbits(val);
        }
    }
}

// ---------------------------------------------------------------------------
extern "C" void kernel_launch(void* const* d_in, const int* in_sizes, int n_in,
                              void* d_out, int out_size, void* d_ws, size_t ws_size,
                              hipStream_t stream) {
    const float* q  = (const float*)d_in[0];
    const float* k  = (const float*)d_in[1];
    const float* v  = (const float*)d_in[2];
    const float* Wq = (const float*)d_in[3];
    const float* Wk = (const float*)d_in[4];
    const float* Wv = (const float*)d_in[5];
    const float* Wo = (const float*)d_in[6];
    const float* bq = (const float*)d_in[7];
    const float* bk = (const float*)d_in[8];
    const float* bv = (const float*)d_in[9];
    const float* bo = (const float*)d_in[10];
    // d_in[11] = causal mask (known structure; not read)

    // workspace layout (element offsets, bf16 stored as short). Total 64 MB.
    short* wsb = (short*)d_ws;
    short* Wb  = wsb;                       // 4 x 1048576  (Wq^T,Wk^T,Wv^T,Wo^T)
    short* Xb  = Wb + 4 * 1048576;          // 3 x 4194304  (q,k,v bf16)
    short* Qp  = Xb + 3 * 4194304;          // 4194304  (B,S,H,D), scales folded
    short* Kp  = Qp + 4194304;              // 4194304  (B,S,H,D)
    short* VpT = Kp + 4194304;              // 4194304  (B,H,D,S)
    short* Ctx = VpT + 4194304;             // 4194304  (B,S,H,D)

    cvt_all<<<13312, 256, 0, stream>>>(q, k, v, Wq, Wk, Wv, Wo, Xb, Wb);
    gemm_qkv<<<768, 512, 0, stream>>>(Xb, Wb, bq, bk, bv, Qp);
    attn_kernel<<<512, 512, 0, stream>>>(Qp, Kp, VpT, Ctx);
    gemm_o<<<256, 512, 0, stream>>>(Ctx, Wb + 3 * 1048576, bo, (float*)d_out);
}

// Round 13
// 226.942 us; speedup vs baseline: 1.0783x; 1.0443x over previous
//
#include <hip/hip_runtime.h>
#include <stdint.h>

// Problem constants
#define B_ 2
#define S_ 2048
#define E_ 1024
#define H_ 16
#define D_ 64
// M = B_*S_ = 4096 rows for all projection GEMMs; N=K=1024.

typedef __attribute__((ext_vector_type(8))) short bf16x8;   // 8 bf16 (4 VGPRs) MFMA A/B frag
typedef __attribute__((ext_vector_type(4))) float f32x4;    // MFMA C/D frag
typedef __attribute__((ext_vector_type(4))) short s16x4_t;  // 8B packed bf16 store

// Counted-vmcnt barrier discipline (T4): keep the newest prefetch stages in
// flight across the barrier instead of __syncthreads()'s vmcnt(0) drain.
#define WAITV8 asm volatile("s_waitcnt vmcnt(8)" ::: "memory")
#define WAITV4 asm volatile("s_waitcnt vmcnt(4)" ::: "memory")
#define WAITV2 asm volatile("s_waitcnt vmcnt(2)" ::: "memory")
#define WAITV0 asm volatile("s_waitcnt vmcnt(0)" ::: "memory")
#define BARRIER do { asm volatile("" ::: "memory"); __builtin_amdgcn_s_barrier(); asm volatile("" ::: "memory"); } while (0)

// fp32 -> bf16 RNE (bit trick; inputs finite)
__device__ __forceinline__ short bfbits(float x) {
    union { float f; uint32_t u; } v; v.f = x;
    uint32_t r = v.u + 0x7fffu + ((v.u >> 16) & 1u);
    return (short)(r >> 16);
}
// fp32 -> bf16 truncation (1 op; for P >= 0)
__device__ __forceinline__ short bfbits_trunc(float x) {
    union { float f; uint32_t u; } v; v.f = x;
    return (short)(v.u >> 16);
}

// async global->LDS, 16B per lane. LDS dest = wave-uniform base + lane*16.
__device__ __forceinline__ void async16(const short* g, short* l) {
    __builtin_amdgcn_global_load_lds((const __attribute__((address_space(1))) void*)g,
                                     (__attribute__((address_space(3))) void*)l,
                                     16, 0, 0);
}

// ---------------------------------------------------------------------------
// Kernel 1 (merged): blocks [0,12288) convert q,k,v fp32 -> bf16;
// blocks [12288, 13312) convert + transpose the 4 weights.
// ---------------------------------------------------------------------------
__global__ __launch_bounds__(256) void cvt_all(const float* __restrict__ q,
                                               const float* __restrict__ k,
                                               const float* __restrict__ v,
                                               const float* __restrict__ Wq,
                                               const float* __restrict__ Wk,
                                               const float* __restrict__ Wv,
                                               const float* __restrict__ Wo,
                                               short* __restrict__ dstX,
                                               short* __restrict__ dstW) {
    __shared__ short t[64][72];  // weights path only
    int bid = blockIdx.x;
    if (bid < 12288) {
        const long long NV = 1048576;  // vec4 count per tensor
        long long i = (long long)bid * 256 + threadIdx.x;  // 0 .. 3*NV-1
        const float* src = (i < NV) ? q : (i < 2 * NV) ? k : v;
        long long j = (i >= 2 * NV) ? (i - 2 * NV) : (i >= NV) ? (i - NV) : i;
        float4 x = ((const float4*)src)[j];
        s16x4_t o;
        o[0] = bfbits(x.x); o[1] = bfbits(x.y); o[2] = bfbits(x.z); o[3] = bfbits(x.w);
        ((s16x4_t*)dstX)[i] = o;
        return;
    }
    int wbid = bid - 12288;  // 0..1023
    int z = wbid >> 8;
    const float* W = (z == 0) ? Wq : (z == 1) ? Wk : (z == 2) ? Wv : Wo;
    short* o = dstW + (size_t)z * 1048576;
    int rem = wbid & 255;
    int n0 = (rem & 15) * 64, k0 = (rem >> 4) * 64;
    int tid = threadIdx.x;
    int r = tid >> 4, c4 = tid & 15;
    for (int rep = 0; rep < 4; rep++) {
        int kk = rep * 16 + r;
        float4 x = *(const float4*)&W[(size_t)(k0 + kk) * 1024 + n0 + c4 * 4];
        t[c4 * 4 + 0][kk] = bfbits(x.x);
        t[c4 * 4 + 1][kk] = bfbits(x.y);
        t[c4 * 4 + 2][kk] = bfbits(x.z);
        t[c4 * 4 + 3][kk] = bfbits(x.w);
    }
    __syncthreads();
    int n = tid >> 3, c8 = tid & 7;
    for (int rep = 0; rep < 2; rep++) {
        int nn = rep * 32 + n;
        bf16x8 vv;
        for (int jj = 0; jj < 8; jj++) vv[jj] = t[nn][c8 * 8 + jj];
        *(bf16x8*)&o[(size_t)(n0 + nn) * 1024 + k0 + c8 * 8] = vv;
    }
}

// ---------------------------------------------------------------------------
// GEMM core v6 (triple-buffer, distance-2 prefetch): 256 threads, 128x128
// tile, BK=32, 32 iters. Theory: 1-deep prefetch (~600cyc compute) < HBM
// miss latency (~900cyc, ~28% of stage loads are compulsory misses) ->
// per-iter convoy. Distance-2: stage(t+2) issued at iter t, two stages
// (8 loads/wave) in flight; s_waitcnt vmcnt(8) waits only stage(t).
// LDS 3 x (8+8) KB = 48 KB -> 3 blocks/CU -> ALL 768 blocks resident.
// 16B-slot XOR swizzle (inverse on global source, forward on ds_read).
// mode: 0 bf16 out, 1 bf16 transposed out (V), 2 fp32 out.
// ---------------------------------------------------------------------------
__device__ __forceinline__ void gemm_core(const short* __restrict__ A,
                                          const short* __restrict__ Bt,
                                          const float* __restrict__ bias,
                                          short* __restrict__ outB,
                                          float* __restrict__ outF,
                                          int mode, float scale,
                                          int m0, int n0) {
    __shared__ short As[3][128 * 32];  // [buf][row*32+k] swizzled, 8 KB each
    __shared__ short Bs[3][128 * 32];
    int tid = threadIdx.x, lane = tid & 63, w = tid >> 6;
    int col = lane & 15, quad = lane >> 4;
    int wm = (w >> 1) * 64, wn = (w & 1) * 64;
    f32x4 acc[4][4];
    for (int i = 0; i < 4; i++)
        for (int j = 0; j < 4; j++) acc[i][j] = (f32x4){0.f, 0.f, 0.f, 0.f};

    int r4 = lane >> 2;
    int skoff = ((lane & 3) ^ ((r4 >> 1) & 3)) * 8;  // shorts
    const short* ga = A + (size_t)(m0 + r4) * 1024 + skoff;
    const short* gb = Bt + (size_t)(n0 + r4) * 1024 + skoff;
    int fro = (quad ^ ((col >> 1) & 3)) * 8;  // swizzled 16B slot (shorts)

    auto stage = [&](int t, int b) {  // 4 gload_lds per wave (2 A + 2 B)
        int k0_ = t * 32;
        for (int c = 0; c < 2; ++c) {
            int rb = w * 32 + c * 16;
            async16(ga + (size_t)rb * 1024 + k0_, &As[b][rb * 32]);
            async16(gb + (size_t)rb * 1024 + k0_, &Bs[b][rb * 32]);
        }
    };

    stage(0, 0);
    stage(1, 1);
    __syncthreads();  // prologue: full drain once; buf0,1 ready
    for (int t = 0; t < 32; ++t) {
        int cur = t % 3;
        if (t + 2 < 32) { stage(t + 2, (t + 2) % 3); WAITV8; }  // stage(t) done; t+1,t+2 in flight
        else if (t + 1 < 32) { WAITV4; }                        // stage(t) done; t+1 in flight
        else { WAITV0; }
        BARRIER;  // all waves: buf cur fully staged
        bf16x8 af[4], bfr[4];
        for (int i = 0; i < 4; i++)
            af[i] = *(const bf16x8*)&As[cur][(wm + i * 16 + col) * 32 + fro];
        for (int j = 0; j < 4; j++)
            bfr[j] = *(const bf16x8*)&Bs[cur][(wn + j * 16 + col) * 32 + fro];
        for (int i = 0; i < 4; i++)
            for (int j = 0; j < 4; j++)
                acc[i][j] = __builtin_amdgcn_mfma_f32_16x16x32_bf16(af[i], bfr[j], acc[i][j], 0, 0, 0);
        BARRIER;  // readers of cur done before it is re-staged at t+3
    }

    // epilogue: C/D layout col=lane&15, row=quad*4+reg
    int mbase = m0 + wm + quad * 4;
    for (int i = 0; i < 4; i++) {
        int mb = mbase + i * 16;
        for (int j = 0; j < 4; j++) {
            int n = n0 + wn + j * 16 + col;
            float bv_ = bias[n];
            if (mode == 0) {
                for (int r = 0; r < 4; r++)
                    outB[(size_t)(mb + r) * 1024 + n] = bfbits((acc[i][j][r] + bv_) * scale);
            } else if (mode == 1) {
                int b_ = mb >> 11, s_ = mb & 2047;
                size_t base = (((size_t)(b_ * 16 + (n >> 6)) * 64) + (n & 63)) * 2048 + s_;
                s16x4_t pv;
                for (int r = 0; r < 4; r++) pv[r] = bfbits((acc[i][j][r] + bv_) * scale);
                *(s16x4_t*)&outB[base] = pv;
            } else {
                for (int r = 0; r < 4; r++)
                    outF[(size_t)(mb + r) * 1024 + n] = (acc[i][j][r] + bv_) * scale;
            }
        }
    }
}

// Fused QKV projections: 1D grid 768 blocks x 256 threads, bijective
// XCD-aware swizzle (768 = 8 * 96). 3 blocks/CU -> all resident.
#define QSCALE (0.015625f * 1.44269504088896340736f)
__global__ __launch_bounds__(256, 3) void gemm_qkv(const short* __restrict__ Xb,
                                                   const short* __restrict__ Wb,
                                                   const float* __restrict__ bq,
                                                   const float* __restrict__ bk,
                                                   const float* __restrict__ bv,
                                                   short* __restrict__ Qp) {
    int bid = blockIdx.x;
    int L = (bid & 7) * 96 + (bid >> 3);  // bijective: 768 = 8 * 96
    int z = L >> 8;                        // 0..2
    int rem = L & 255;
    int m0 = (rem >> 3) * 128, n0 = (rem & 7) * 128;
    const short* A = Xb + (size_t)z * 4194304;
    const short* Bt = Wb + (size_t)z * 1048576;
    const float* bias = (z == 0) ? bq : (z == 1) ? bk : bv;
    short* outB = Qp + (size_t)z * 4194304;  // Qp, Kp, VpT contiguous
    gemm_core(A, Bt, bias, outB, nullptr, (z == 2) ? 1 : 0,
              (z == 0) ? QSCALE : 1.0f, m0, n0);
}

// Output projection: 1D grid 256 blocks x 256 threads, XCD chunking.
__global__ __launch_bounds__(256, 3) void gemm_o(const short* __restrict__ Ctx,
                                                 const short* __restrict__ Wob,
                                                 const float* __restrict__ bo,
                                                 float* __restrict__ out) {
    int bid = blockIdx.x;
    int L = (bid & 7) * 32 + (bid >> 3);  // bijective: 256 = 8 * 32
    int m0 = (L >> 3) * 128, n0 = (L & 7) * 128;
    gemm_core(Ctx, Wob, bo, nullptr, out, 2, 1.0f, m0, n0);
}

// ---------------------------------------------------------------------------
// Flash-style causal attention, v11 (unchanged from r11 — counted vmcnt
// gave −7 µs): 8-wave TLP, block 512: waves 0-3 q-tile qx, waves 4-7
// q-tile 31-qx, shared K/V pipeline; stage(t+1) stays in flight across the
// barrier (vmcnt(2)); bijective XCD chunking bh-major; MFMA ones row-sum.
// LDS 50.4 KB -> 3 blocks/CU.
// ---------------------------------------------------------------------------
__device__ __forceinline__ void stage_kv8(const short* __restrict__ Kp,
                                          const short* __restrict__ VpT,
                                          short* Kbuf, short* Vbuf,
                                          int b, int bh, int h, int kv0,
                                          int tid) {
    int row = tid >> 3;                    // 0..63 (512 threads cover tile)
    int sk = ((tid & 7) ^ (row & 7)) * 8;  // inverse-swizzled 16B slot (shorts)
    int wbase = (tid >> 6) * 512;          // wave-uniform LDS base (shorts)
    async16(Kp + (size_t)(b * 2048 + kv0 + row) * 1024 + h * 64 + sk, &Kbuf[wbase]);
    async16(VpT + (size_t)(bh * 64 + row) * 2048 + kv0 + sk, &Vbuf[wbase]);
}

__global__ __launch_bounds__(512) void attn_kernel(const short* __restrict__ Qp,
                                                   const short* __restrict__ Kp,
                                                   const short* __restrict__ VpT,
                                                   short* __restrict__ Ctx) {
    __shared__ short Kt[2][64 * 64];  // [buf][kv][d] swizzled, 8 KB each
    __shared__ short Vt[2][64 * 64];  // [buf][d][kv] swizzled
    __shared__ short Pl[8][16 * 72];  // per-wave P, [q_local][kv(72 stride)]
    int tid = threadIdx.x, lane = tid & 63, w = tid >> 6;
    int col = lane & 15, quad = lane >> 4;
    int c7 = col & 7;
    int bid = blockIdx.x;
    int L = (bid & 7) * 64 + (bid >> 3);  // bijective XCD chunking (512 = 8*64)
    int qx = L & 15, bh = L >> 4;          // 4 bh per XCD -> K/V L2-resident
    int b = bh >> 4, h = bh & 15;
    int wi = w & 3;
    int qt = (w < 4) ? qx : (31 - qx);     // wave's q-tile
    int myN = qt + 1;                      // wave's causal kv-tile count
    int nB = 32 - qx;                      // block loop bound (= max)
    int qrow = qt * 64 + wi * 16;          // wave's q base

    bf16x8 ones;
    for (int j = 0; j < 8; j++) ones[j] = (short)0x3F80;  // bf16 1.0

    bf16x8 aq0, aq1;
    {
        const short* qa = Qp + ((size_t)(b * 2048 + qrow + col)) * 1024 + h * 64;
        aq0 = *(const bf16x8*)(qa + quad * 8);
        aq1 = *(const bf16x8*)(qa + 32 + quad * 8);
    }
    f32x4 o[4];
    for (int dj = 0; dj < 4; dj++) o[dj] = (f32x4){0.f, 0.f, 0.f, 0.f};
    f32x4 psv = (f32x4){0.f, 0.f, 0.f, 0.f};  // row-sums via MFMA ones

    short* Plw = Pl[w];

    stage_kv8(Kp, VpT, Kt[0], Vt[0], b, bh, h, 0, tid);

    for (int t = 0; t < nB; t++) {
        if (t + 1 < nB) {
            stage_kv8(Kp, VpT, Kt[(t + 1) & 1], Vt[(t + 1) & 1], b, bh, h,
                      (t + 1) * 64, tid);
            WAITV2;  // stage(t) done; stage(t+1) stays in flight
        } else {
            WAITV0;
        }
        BARRIER;  // all waves: buf t&1 fully staged
        if (t < myN) {  // wave-uniform predicate (A-waves idle past nA)
            const short* Kb = Kt[t & 1];
            const short* Vb = Vt[t & 1];

            f32x4 sf[4];
            for (int i = 0; i < 4; i++) sf[i] = (f32x4){0.f, 0.f, 0.f, 0.f};
            __builtin_amdgcn_s_setprio(1);
            for (int ks = 0; ks < 2; ks++) {
                bf16x8 bq_ = ks ? aq1 : aq0;
                int sl = ((ks * 4 + quad) ^ c7) * 8;
                for (int i = 0; i < 4; i++) {
                    bf16x8 ak_ = *(const bf16x8*)&Kb[(i * 16 + col) * 64 + sl];
                    sf[i] = __builtin_amdgcn_mfma_f32_16x16x32_bf16(ak_, bq_, sf[i], 0, 0, 0);
                }
            }
            __builtin_amdgcn_s_setprio(0);
            if (t == myN - 1) {
                int qg = qrow + col;
                for (int i = 0; i < 4; i++) {
                    int kvg = t * 64 + i * 16 + quad * 4;
                    for (int r = 0; r < 4; r++)
                        if (kvg + r > qg) sf[i][r] = -3.0e38f;
                }
            }
            for (int i = 0; i < 4; i++) {
                s16x4_t pw;
                for (int r = 0; r < 4; r++)
                    pw[r] = bfbits_trunc(exp2f(sf[i][r]));
                *(s16x4_t*)&Plw[col * 72 + i * 16 + quad * 4] = pw;
            }
            __builtin_amdgcn_s_setprio(1);
            for (int ks = 0; ks < 2; ks++) {
                bf16x8 ap = *(const bf16x8*)&Plw[col * 72 + ks * 32 + quad * 8];
                int sl = ((ks * 4 + quad) ^ c7) * 8;
                psv = __builtin_amdgcn_mfma_f32_16x16x32_bf16(ap, ones, psv, 0, 0, 0);
                for (int dj = 0; dj < 4; dj++) {
                    bf16x8 bv_ = *(const bf16x8*)&Vb[(dj * 16 + col) * 64 + sl];
                    o[dj] = __builtin_amdgcn_mfma_f32_16x16x32_bf16(ap, bv_, o[dj], 0, 0, 0);
                }
            }
            __builtin_amdgcn_s_setprio(0);
        }
        BARRIER;  // readers of buf t&1 done before it is re-staged at t+2
    }
    float inv[4];
    for (int r = 0; r < 4; r++) inv[r] = 1.0f / psv[r];
    for (int r = 0; r < 4; r++) {
        for (int dj = 0; dj < 4; dj++) {
            float val = o[dj][r] * inv[r];
            Ctx[((size_t)(b * 2048 + qrow + quad * 4 + r)) * 1024 + h * 64 + dj * 16 + col] = bfbits(val);
        }
    }
}

// ---------------------------------------------------------------------------
extern "C" void kernel_launch(void* const* d_in, const int* in_sizes, int n_in,
                              void* d_out, int out_size, void* d_ws, size_t ws_size,
                              hipStream_t stream) {
    const float* q  = (const float*)d_in[0];
    const float* k  = (const float*)d_in[1];
    const float* v  = (const float*)d_in[2];
    const float* Wq = (const float*)d_in[3];
    const float* Wk = (const float*)d_in[4];
    const float* Wv = (const float*)d_in[5];
    const float* Wo = (const float*)d_in[6];
    const float* bq = (const float*)d_in[7];
    const float* bk = (const float*)d_in[8];
    const float* bv = (const float*)d_in[9];
    const float* bo = (const float*)d_in[10];
    // d_in[11] = causal mask (known structure; not read)

    // workspace layout (element offsets, bf16 stored as short). Total 64 MB.
    short* wsb = (short*)d_ws;
    short* Wb  = wsb;                       // 4 x 1048576  (Wq^T,Wk^T,Wv^T,Wo^T)
    short* Xb  = Wb + 4 * 1048576;          // 3 x 4194304  (q,k,v bf16)
    short* Qp  = Xb + 3 * 4194304;          // 4194304  (B,S,H,D), scales folded
    short* Kp  = Qp + 4194304;              // 4194304  (B,S,H,D)
    short* VpT = Kp + 4194304;              // 4194304  (B,H,D,S)
    short* Ctx = VpT + 4194304;             // 4194304  (B,S,H,D)

    cvt_all<<<13312, 256, 0, stream>>>(q, k, v, Wq, Wk, Wv, Wo, Xb, Wb);
    gemm_qkv<<<768, 256, 0, stream>>>(Xb, Wb, bq, bk, bv, Qp);
    attn_kernel<<<512, 512, 0, stream>>>(Qp, Kp, VpT, Ctx);
    gemm_o<<<256, 256, 0, stream>>>(Ctx, Wb + 3 * 1048576, bo, (float*)d_out);
}